// Round 4
// baseline (387.124 us; speedup 1.0000x reference)
//
#include <hip/hip_runtime.h>
#include <math.h>

// Sobel gradient magnitude: in (176, 512, 512) f32 -> out (176, 510, 510) f32
// mag = sqrt((0.5*gx)^2 + (0.5*gy)^2), VALID 3x3 Sobel.
//
// Register-rolling vertical stencil, software-pipelined one row ahead.
// Each block = 128 threads, one (bc, 30-row output strip). Each thread owns
// 4 output columns, keeps 3 live input rows x 8 floats in registers plus one
// in-flight prefetch row. Separable reformulation:
//   t[c]  = r0[c] + 2*r1[c] + r2[c]  (vertical smooth) -> gx = t[c]-t[c+2]
//   sd[c] = r0[c] - r2[c]            (vertical diff)   -> gy = sd[c]+2*sd[c+1]+sd[c+2]

#define ROWS_PER_BLOCK 30   // 510 = 17 * 30 exactly

// Native clang vector type: __builtin_nontemporal_store requires a real
// vector (HIP's float2 is a class and is rejected).
typedef float floatx2 __attribute__((ext_vector_type(2)));

__global__ __launch_bounds__(128) void sobel_mag_kernel(
    const float* __restrict__ in, float* __restrict__ out)
{
    const int tid   = threadIdx.x;      // 0..127
    const int strip = blockIdx.x;       // 0..16
    const int bc    = blockIdx.y;       // 0..175
    const int W  = 512;
    const int OW = 510;
    const int ox = tid * 4;             // output column base: 0..508

    const long long in_base  = (long long)bc * (512LL * 512LL)
                             + (long long)(strip * ROWS_PER_BLOCK) * W + ox;
    const long long out_base = (long long)bc * (510LL * 510LL)
                             + (long long)(strip * ROWS_PER_BLOCK) * OW + ox;

    // tid==127: ox=508; the "hi" float4 (cols 512..515) would run off the row
    // (and off the buffer on the last row). Its data only feeds output cols
    // 510/511 which don't exist, so substitute zeros.
    const bool load_hi = (ox + 4) < W;

    float a0[8], a1[8], a2[8], nx[8];

    // Prologue: rows 0, 1, 2 of the strip resident.
    {
        float4 lo = *reinterpret_cast<const float4*>(in + in_base);
        float4 hi = load_hi ? *reinterpret_cast<const float4*>(in + in_base + 4)
                            : make_float4(0.f, 0.f, 0.f, 0.f);
        a0[0]=lo.x; a0[1]=lo.y; a0[2]=lo.z; a0[3]=lo.w;
        a0[4]=hi.x; a0[5]=hi.y; a0[6]=hi.z; a0[7]=hi.w;
    }
    {
        float4 lo = *reinterpret_cast<const float4*>(in + in_base + W);
        float4 hi = load_hi ? *reinterpret_cast<const float4*>(in + in_base + W + 4)
                            : make_float4(0.f, 0.f, 0.f, 0.f);
        a1[0]=lo.x; a1[1]=lo.y; a1[2]=lo.z; a1[3]=lo.w;
        a1[4]=hi.x; a1[5]=hi.y; a1[6]=hi.z; a1[7]=hi.w;
    }
    {
        float4 lo = *reinterpret_cast<const float4*>(in + in_base + 2 * W);
        float4 hi = load_hi ? *reinterpret_cast<const float4*>(in + in_base + 2 * W + 4)
                            : make_float4(0.f, 0.f, 0.f, 0.f);
        a2[0]=lo.x; a2[1]=lo.y; a2[2]=lo.z; a2[3]=lo.w;
        a2[4]=hi.x; a2[5]=hi.y; a2[6]=hi.z; a2[7]=hi.w;
    }

    for (int s = 0; s < ROWS_PER_BLOCK; ++s) {
        // Prefetch row s+3 (next iteration's bottom row) BEFORE computing,
        // so its latency hides under this iteration's math + store.
        if (s + 1 < ROWS_PER_BLOCK) {
            const float* rp = in + in_base + (long long)(s + 3) * W;
            float4 lo = *reinterpret_cast<const float4*>(rp);
            float4 hi = load_hi ? *reinterpret_cast<const float4*>(rp + 4)
                                : make_float4(0.f, 0.f, 0.f, 0.f);
            nx[0]=lo.x; nx[1]=lo.y; nx[2]=lo.z; nx[3]=lo.w;
            nx[4]=hi.x; nx[5]=hi.y; nx[6]=hi.z; nx[7]=hi.w;
        }

        float t[6], sd[6];
        #pragma unroll
        for (int c = 0; c < 6; ++c) {
            t[c]  = a0[c] + 2.0f * a1[c] + a2[c];
            sd[c] = a0[c] - a2[c];
        }

        float m[4];
        #pragma unroll
        for (int k = 0; k < 4; ++k) {
            float gx = t[k] - t[k + 2];
            float gy = sd[k] + 2.0f * sd[k + 1] + sd[k + 2];
            float hx = 0.5f * gx;
            float hy = 0.5f * gy;
            m[k] = sqrtf(hx * hx + hy * hy);
        }

        // Store: out row base is always 8B-aligned (bc*260100 even, oy*510
        // even, ox even) but NOT 16B-aligned on odd rows -> float2 stores.
        // Output is never re-read: nontemporal keeps L2 for input halo rows.
        float* op = out + out_base + (long long)s * OW;
        floatx2 p0; p0.x = m[0]; p0.y = m[1];
        __builtin_nontemporal_store(p0, reinterpret_cast<floatx2*>(op));
        if (ox + 2 < OW) {
            floatx2 p1; p1.x = m[2]; p1.y = m[3];
            __builtin_nontemporal_store(p1, reinterpret_cast<floatx2*>(op + 2));
        }

        // Rotate rows; promote prefetched row.
        #pragma unroll
        for (int c = 0; c < 8; ++c) { a0[c] = a1[c]; a1[c] = a2[c]; a2[c] = nx[c]; }
    }
}

extern "C" void kernel_launch(void* const* d_in, const int* in_sizes, int n_in,
                              void* d_out, int out_size, void* d_ws, size_t ws_size,
                              hipStream_t stream) {
    const float* in = (const float*)d_in[0];
    float* out = (float*)d_out;

    dim3 block(128, 1, 1);
    dim3 grid(17, 176, 1);   // 17 row-strips x (B*C=176)
    sobel_mag_kernel<<<grid, block, 0, stream>>>(in, out);
}

// Round 5
// 314.856 us; speedup vs baseline: 1.2295x; 1.2295x over previous
//
#include <hip/hip_runtime.h>
#include <math.h>

// Sobel gradient magnitude: in (176, 512, 512) f32 -> out (176, 510, 510) f32
// mag = sqrt((0.5*gx)^2 + (0.5*gy)^2), VALID 3x3 Sobel.
//
// Batch-tile structure (v2): each block = 128 threads computes a 6x512 output
// tile. All 8 input rows are loaded up-front as 16 INDEPENDENT float4 loads
// per thread (256B in flight per wave) -- maximizing memory-level parallelism,
// which round-4 counters showed was the limiter (27% HBM BW with depth-1
// rolling prefetch). The 8/6 = 1.33x vertical read amplification is absorbed
// by the 256MB L3 (input is fully L3-resident: 184MB; measured FETCH was only
// 96MB). Plain cached stores: round-4 nontemporal stores caused 1.65x write
// amplification (partial-sector HBM writes without L2 combining).
//
// Separable reformulation per output row:
//   t[c]  = r0[c] + 2*r1[c] + r2[c]  (vertical smooth) -> gx = t[c]-t[c+2]
//   sd[c] = r0[c] - r2[c]            (vertical diff)   -> gy = sd[c]+2*sd[c+1]+sd[c+2]

#define OUT_ROWS 6   // 510 = 85 * 6 exactly
#define IN_ROWS  8

__global__ __launch_bounds__(128) void sobel_mag_kernel(
    const float* __restrict__ in, float* __restrict__ out)
{
    const int tid   = threadIdx.x;      // 0..127
    const int strip = blockIdx.x;       // 0..84
    const int bc    = blockIdx.y;       // 0..175
    const int W  = 512;
    const int OW = 510;
    const int ox = tid * 4;             // output column base: 0..508

    const long long in_base  = (long long)bc * (512LL * 512LL)
                             + (long long)(strip * OUT_ROWS) * W + ox;
    const long long out_base = (long long)bc * (510LL * 510LL)
                             + (long long)(strip * OUT_ROWS) * OW + ox;

    // tid==127: ox=508; the "hi" float4 (cols 512..515) would run off the row.
    // Its data only feeds output cols 510/511 which don't exist -> zeros.
    const bool load_hi = (ox + 4) < W;

    // Load the whole 8-row input slab: 16 independent float4 loads.
    float r[IN_ROWS][8];
    #pragma unroll
    for (int k = 0; k < IN_ROWS; ++k) {
        const float* rp = in + in_base + (long long)k * W;
        float4 lo = *reinterpret_cast<const float4*>(rp);
        float4 hi = load_hi ? *reinterpret_cast<const float4*>(rp + 4)
                            : make_float4(0.f, 0.f, 0.f, 0.f);
        r[k][0]=lo.x; r[k][1]=lo.y; r[k][2]=lo.z; r[k][3]=lo.w;
        r[k][4]=hi.x; r[k][5]=hi.y; r[k][6]=hi.z; r[k][7]=hi.w;
    }

    // Compute + store 6 output rows.
    #pragma unroll
    for (int orow = 0; orow < OUT_ROWS; ++orow) {
        float t[6], sd[6];
        #pragma unroll
        for (int c = 0; c < 6; ++c) {
            t[c]  = r[orow][c] + 2.0f * r[orow + 1][c] + r[orow + 2][c];
            sd[c] = r[orow][c] - r[orow + 2][c];
        }

        float m[4];
        #pragma unroll
        for (int k = 0; k < 4; ++k) {
            float gx = t[k] - t[k + 2];
            float gy = sd[k] + 2.0f * sd[k + 1] + sd[k + 2];
            float hx = 0.5f * gx;
            float hy = 0.5f * gy;
            m[k] = sqrtf(hx * hx + hy * hy);
        }

        // Out row base is always 8B-aligned (bc*260100 even, oy*510 even,
        // ox even) but not 16B-aligned on odd rows -> float2 stores.
        // Plain cached stores: L2 combines the store1/store2 interleave into
        // full-line evictions (nt stores caused 1.65x write amplification).
        float* op = out + out_base + (long long)orow * OW;
        *reinterpret_cast<float2*>(op) = make_float2(m[0], m[1]);
        if (ox + 2 < OW) {
            *reinterpret_cast<float2*>(op + 2) = make_float2(m[2], m[3]);
        }
    }
}

extern "C" void kernel_launch(void* const* d_in, const int* in_sizes, int n_in,
                              void* d_out, int out_size, void* d_ws, size_t ws_size,
                              hipStream_t stream) {
    const float* in = (const float*)d_in[0];
    float* out = (float*)d_out;

    dim3 block(128, 1, 1);
    dim3 grid(85, 176, 1);   // 85 row-strips (510/6) x (B*C=176)
    sobel_mag_kernel<<<grid, block, 0, stream>>>(in, out);
}

// Round 7
// 308.033 us; speedup vs baseline: 1.2568x; 1.0222x over previous
//
#include <hip/hip_runtime.h>
#include <math.h>

// Sobel gradient magnitude: in (176, 512, 512) f32 -> out (176, 510, 510) f32
// mag = sqrt((0.5*gx)^2 + (0.5*gy)^2), VALID 3x3 Sobel.
//
// v3: batch-tile (6x512 out per 128-thread block) with NON-OVERLAPPING loads.
// v2 loaded every 16B twice (lane i's hi float4 == lane i+1's lo float4).
// Now each lane loads exactly its 4 columns (8 independent float4 loads,
// full MLP) and obtains the 2 halo columns from lane+1 via __shfl_down.
// The last lane of each wave loads its 8B halo directly (cross-wave).
// sqrt via __builtin_amdgcn_sqrtf (raw v_sqrt_f32, ~1ulp; tolerance 0.03).
// Plain cached stores (nontemporal caused 1.65x write amplification, r4).
//
// Separable reformulation per output row:
//   t[c]  = r0[c] + 2*r1[c] + r2[c]  (vertical smooth) -> gx = t[c]-t[c+2]
//   sd[c] = r0[c] - r2[c]            (vertical diff)   -> gy = sd[c]+2*sd[c+1]+sd[c+2]

#define OUT_ROWS 6   // 510 = 85 * 6 exactly
#define IN_ROWS  8

__global__ __launch_bounds__(128) void sobel_mag_kernel(
    const float* __restrict__ in, float* __restrict__ out)
{
    const int tid   = threadIdx.x;      // 0..127
    const int lane  = tid & 63;
    const int strip = blockIdx.x;       // 0..84
    const int bc    = blockIdx.y;       // 0..175
    const int W  = 512;
    const int OW = 510;
    const int ox = tid * 4;             // output column base: 0..508

    const long long in_base  = (long long)bc * (512LL * 512LL)
                             + (long long)(strip * OUT_ROWS) * W + ox;
    const long long out_base = (long long)bc * (510LL * 510LL)
                             + (long long)(strip * OUT_ROWS) * OW + ox;

    // Own 4 columns per row: 8 independent float4 loads (max MLP, no overlap).
    float e[IN_ROWS][4];
    #pragma unroll
    for (int k = 0; k < IN_ROWS; ++k) {
        const float4 lo = *reinterpret_cast<const float4*>(
            in + in_base + (long long)k * W);
        e[k][0] = lo.x; e[k][1] = lo.y; e[k][2] = lo.z; e[k][3] = lo.w;
    }

    // Halo columns ox+4, ox+5. For lanes 0..62: they live in lane+1's e[k][0..1]
    // (shuffle). For lane 63: cross-wave -> direct 8B load (tid 127's halo is
    // cols 512/513 which don't exist and only feed discarded outputs -> zeros).
    const bool is_last_lane = (lane == 63);
    const bool halo_valid   = (ox + 4) < W;   // false only for tid 127

    float h[IN_ROWS][2];
    if (is_last_lane && halo_valid) {
        #pragma unroll
        for (int k = 0; k < IN_ROWS; ++k) {
            const float2 v = *reinterpret_cast<const float2*>(
                in + in_base + (long long)k * W + 4);
            h[k][0] = v.x; h[k][1] = v.y;
        }
    } else {
        #pragma unroll
        for (int k = 0; k < IN_ROWS; ++k) { h[k][0] = 0.f; h[k][1] = 0.f; }
    }

    #pragma unroll
    for (int k = 0; k < IN_ROWS; ++k) {
        // All lanes execute the shuffle (lane 63 is the source for lane 62);
        // lane 63 keeps its directly-loaded halo.
        const float s0 = __shfl_down(e[k][0], 1);
        const float s1 = __shfl_down(e[k][1], 1);
        if (!is_last_lane) { h[k][0] = s0; h[k][1] = s1; }
    }

    // Compute + store 6 output rows. Column c in 0..5 maps to
    // {e[k][0..3], h[k][0..1]}.
    #pragma unroll
    for (int orow = 0; orow < OUT_ROWS; ++orow) {
        float t[6], sd[6];
        #pragma unroll
        for (int c = 0; c < 4; ++c) {
            t[c]  = e[orow][c] + 2.0f * e[orow + 1][c] + e[orow + 2][c];
            sd[c] = e[orow][c] - e[orow + 2][c];
        }
        #pragma unroll
        for (int c = 0; c < 2; ++c) {
            t[4 + c]  = h[orow][c] + 2.0f * h[orow + 1][c] + h[orow + 2][c];
            sd[4 + c] = h[orow][c] - h[orow + 2][c];
        }

        float m[4];
        #pragma unroll
        for (int k = 0; k < 4; ++k) {
            const float gx = t[k] - t[k + 2];
            const float gy = sd[k] + 2.0f * sd[k + 1] + sd[k + 2];
            const float hx = 0.5f * gx;
            const float hy = 0.5f * gy;
            m[k] = __builtin_amdgcn_sqrtf(hx * hx + hy * hy);
        }

        // Out row base is always 8B-aligned (bc*260100 even, oy*510 even,
        // ox even) but not 16B-aligned on odd rows -> float2 stores.
        float* op = out + out_base + (long long)orow * OW;
        *reinterpret_cast<float2*>(op) = make_float2(m[0], m[1]);
        if (ox + 2 < OW) {
            *reinterpret_cast<float2*>(op + 2) = make_float2(m[2], m[3]);
        }
    }
}

extern "C" void kernel_launch(void* const* d_in, const int* in_sizes, int n_in,
                              void* d_out, int out_size, void* d_ws, size_t ws_size,
                              hipStream_t stream) {
    const float* in = (const float*)d_in[0];
    float* out = (float*)d_out;

    dim3 block(128, 1, 1);
    dim3 grid(85, 176, 1);   // 85 row-strips (510/6) x (B*C=176)
    sobel_mag_kernel<<<grid, block, 0, stream>>>(in, out);
}